// Round 4
// baseline (2357.471 us; speedup 1.0000x reference)
//
#include <hip/hip_runtime.h>
#include <math.h>

#define GRIDN    128
#define NRAYS    16384
#define STEPSZ   0.5f
#define MAXSTEPS 320
#define NVOX     (GRIDN * GRIDN * GRIDN)
// fp16 record: 32 halves (64 B) per VOXEL: [0]=density, [1..27]=sh, pad.
// Voxel-indexed (links folded in at repack time); empty voxels = zero record.
#define PACK_BYTES ((size_t)(NVOX + 1) * 64)

// ---- tile/segment decomposition for the march ----
#define TILES  256                  // 16x16 tiles of 8x8 pixels
#define WPB    4                    // waves per block

static inline size_t part_bytes(int nseg) {
    return (size_t)nseg * TILES * 64 * 8 * 4;
}

typedef _Float16 half8 __attribute__((ext_vector_type(8)));

// ---------------------------------------------------------------------------
// Prologue: voxel-indexed repack, v3. Records are assembled in LDS and
// stored with fully-coalesced contiguous dwordx4 (the old per-lane 64B-stride
// stores touched 64 partial lines per instruction = 4x transaction inflation
// on 134 MB). Reads stay coalesced; LDS scatter is ~2 lanes/bank (free).
// ---------------------------------------------------------------------------
__global__ __launch_bounds__(256, 8)
void repack_kernel(const int*   __restrict__ links,
                   const float* __restrict__ density,
                   const float* __restrict__ sh,
                   _Float16*    __restrict__ pack)
{
    __shared__ _Float16 rec[256 * 32];   // 16 KB: 256 records
    const int tid   = threadIdx.x;
    const int vbase = blockIdx.x * 256;

    // Phase 1: coalesced read of the block's 256 sh rows (6912 floats),
    // fp16-convert, scatter into record layout in LDS.
    const float* src = sh + (size_t)vbase * 27;
    #pragma unroll
    for (int j = 0; j < 27; j++) {
        const int n   = j * 256 + tid;
        const float v = src[n];
        const int row = n / 27;            // magic-mul
        const int k   = n - row * 27;
        rec[row * 32 + 1 + k] = (_Float16)v;
    }

    const int lnk  = links[vbase + tid];
    const float dens = (lnk >= 0) ? density[lnk] : 0.0f;

    __syncthreads();

    // General-links fixup: if lnk != own row, capture correct data first.
    // (Identity links — the common case — never takes this path.)
    const bool fix = (lnk >= 0) && (lnk != vbase + tid);
    float tmp[27];
    if (fix) {
        if (lnk >= vbase && lnk < vbase + 256) {
            const _Float16* s = rec + (lnk - vbase) * 32 + 1;
            #pragma unroll
            for (int k = 0; k < 27; k++) tmp[k] = (float)s[k];
        } else {
            const float* row = sh + (size_t)lnk * 27;
            #pragma unroll
            for (int k = 0; k < 27; k++) tmp[k] = row[k];
        }
    }
    __syncthreads();

    _Float16* my = rec + tid * 32;
    my[0]  = (_Float16)dens;
    my[28] = (_Float16)0.0f; my[29] = (_Float16)0.0f;
    my[30] = (_Float16)0.0f; my[31] = (_Float16)0.0f;
    if (lnk < 0) {
        #pragma unroll
        for (int k = 0; k < 27; k++) my[1 + k] = (_Float16)0.0f;
    } else if (fix) {
        #pragma unroll
        for (int k = 0; k < 27; k++) my[1 + k] = (_Float16)tmp[k];
    }
    __syncthreads();

    // Phase 3: fully coalesced LDS->global copy (16 KB / block).
    const uint4* ls = (const uint4*)rec;
    uint4* gd = (uint4*)(pack + (size_t)vbase * 32);
    #pragma unroll
    for (int i = 0; i < 4; i++)
        gd[i * 256 + tid] = ls[i * 256 + tid];
}

// ---------------------------------------------------------------------------
// March partials: one wave = 64 adjacent rays (8x8 pixel tile) at ONE segment.
// Incremental corner cache: on a single-axis cell step, shuffle 4 projected
// corner values in registers and gather only the 4 new corners (~45% fewer
// gather bytes; the gather delivery path is the measured wall).
// Partials split into two SoA float4 arrays so stores/loads coalesce.
// ---------------------------------------------------------------------------
#define LOADC(c, voxidx) do {                                                  \
    const half8* pr_ = (const half8*)(pack + (size_t)(voxidx) * 32);           \
    const half8 h0 = pr_[0], h1 = pr_[1], h2 = pr_[2], h3 = pr_[3];            \
    csig[c] = (float)h0[0];                                                    \
    cr0[c] = shm[0]*(float)h0[1] + shm[1]*(float)h0[2] + shm[2]*(float)h0[3]   \
           + shm[3]*(float)h0[4] + shm[4]*(float)h0[5] + shm[5]*(float)h0[6]   \
           + shm[6]*(float)h0[7] + shm[7]*(float)h1[0] + shm[8]*(float)h1[1];  \
    cr1[c] = shm[0]*(float)h1[2] + shm[1]*(float)h1[3] + shm[2]*(float)h1[4]   \
           + shm[3]*(float)h1[5] + shm[4]*(float)h1[6] + shm[5]*(float)h1[7]   \
           + shm[6]*(float)h2[0] + shm[7]*(float)h2[1] + shm[8]*(float)h2[2];  \
    cr2[c] = shm[0]*(float)h2[3] + shm[1]*(float)h2[4] + shm[2]*(float)h2[5]   \
           + shm[3]*(float)h2[6] + shm[4]*(float)h2[7] + shm[5]*(float)h3[0]   \
           + shm[6]*(float)h3[1] + shm[7]*(float)h3[2] + shm[8]*(float)h3[3];  \
} while (0)

#define MOVC(d, s) do { csig[d]=csig[s]; cr0[d]=cr0[s];                        \
                        cr1[d]=cr1[s];   cr2[d]=cr2[s]; } while (0)

template <int NSEG>
__global__ __launch_bounds__(256, 8)
void march_part_kernel(const float* __restrict__ origins,
                       const float* __restrict__ dirs,
                       const _Float16* __restrict__ pack,
                       float* __restrict__ parts)
{
    constexpr int SPSEG = MAXSTEPS / NSEG;
    const int lane = threadIdx.x & 63;
    const int gw   = blockIdx.x * WPB + (threadIdx.x >> 6);
    const int seg  = gw >> 8;              // seg-major dispatch: resident
    const int tile = gw & (TILES - 1);     //  waves share a depth slab
    const int ray  = (((tile >> 4) * 8 + (lane >> 3)) << 7)
                   + ((tile & 15) << 3) + (lane & 7);

    // ---- ray setup ----
    const float owx = origins[ray * 3 + 0];
    const float owy = origins[ray * 3 + 1];
    const float owz = origins[ray * 3 + 2];
    const float dwx = dirs[ray * 3 + 0];
    const float dwy = dirs[ray * 3 + 1];
    const float dwz = dirs[ray * 3 + 2];

    const float invn = 1.0f / sqrtf(dwx * dwx + dwy * dwy + dwz * dwz);
    const float vx = dwx * invn, vy = dwy * invn, vz = dwz * invn;

    const float ox = 63.5f + owx * 64.0f;
    const float oy = 63.5f + owy * 64.0f;
    const float oz = 63.5f + owz * 64.0f;

    const float sxx = vx * 64.0f, syy = vy * 64.0f, szz = vz * 64.0f;
    const float ds  = 1.0f / sqrtf(sxx * sxx + syy * syy + szz * szz);
    const float dx = sxx * ds, dy = syy * ds, dz = szz * ds;

    float shm[9];
    shm[0] = 0.28209479177387814f;
    shm[1] = -0.4886025119029199f * vy;
    shm[2] =  0.4886025119029199f * vz;
    shm[3] = -0.4886025119029199f * vx;
    shm[4] =  1.0925484305920792f * vx * vy;
    shm[5] = -1.0925484305920792f * vy * vz;
    shm[6] =  0.31539156525252005f * (2.0f * vz * vz - vx * vx - vy * vy);
    shm[7] = -1.0925484305920792f * vx * vz;
    shm[8] =  0.5462742152960396f * (vx * vx - vy * vy);

    float t0 = 0.0f, tmax = 1e9f;
    {
        const float o3[3] = { ox, oy, oz };
        const float d3[3] = { dx, dy, dz };
        #pragma unroll
        for (int a = 0; a < 3; a++) {
            if (d3[a] != 0.0f) {
                float inv = 1.0f / d3[a];
                float ta = (-0.5f  - o3[a]) * inv;
                float tb = (127.5f - o3[a]) * inv;
                t0   = fmaxf(t0,   fminf(ta, tb));
                tmax = fminf(tmax, fmaxf(ta, tb));
            }
        }
    }

    float ll = 0.0f;
    float light = 1.0f;
    float aR = 0, aG = 0, aB = 0, aA = 0, aD1 = 0, aD2 = 0;

    int ccx = -1000, ccy = -1000, ccz = -1000;
    float csig[8], cr0[8], cr1[8], cr2[8];

    const int k0 = seg * SPSEG;
    for (int i = 0; i < SPSEG; i++) {
        const float t = t0 + (float)(k0 + i) * STEPSZ;
        if (t > tmax) break;

        float px = fminf(fmaxf(ox + t * dx, 0.0f), 127.0f);
        float py = fminf(fmaxf(oy + t * dy, 0.0f), 127.0f);
        float pz = fminf(fmaxf(oz + t * dz, 0.0f), 127.0f);
        const int lx = min(max((int)px, 0), 126);
        const int ly = min(max((int)py, 0), 126);
        const int lz = min(max((int)pz, 0), 126);
        const float fx = px - (float)lx;
        const float fy = py - (float)ly;
        const float fz = pz - (float)lz;

        if (lx != ccx || ly != ccy || lz != ccz) {
            const int base = (lx << 14) | (ly << 7) | lz;
            const int adx = lx - ccx, ady = ly - ccy, adz = lz - ccz;
            if (adx == 0 && ady == 0 && adz == 1) {
                MOVC(0,1); MOVC(2,3); MOVC(4,5); MOVC(6,7);
                LOADC(1, base + 1);     LOADC(3, base + 129);
                LOADC(5, base + 16385); LOADC(7, base + 16513);
            } else if (adx == 0 && ady == 0 && adz == -1) {
                MOVC(1,0); MOVC(3,2); MOVC(5,4); MOVC(7,6);
                LOADC(0, base);         LOADC(2, base + 128);
                LOADC(4, base + 16384); LOADC(6, base + 16512);
            } else if (adx == 0 && adz == 0 && ady == 1) {
                MOVC(0,2); MOVC(1,3); MOVC(4,6); MOVC(5,7);
                LOADC(2, base + 128);   LOADC(3, base + 129);
                LOADC(6, base + 16512); LOADC(7, base + 16513);
            } else if (adx == 0 && adz == 0 && ady == -1) {
                MOVC(2,0); MOVC(3,1); MOVC(6,4); MOVC(7,5);
                LOADC(0, base);         LOADC(1, base + 1);
                LOADC(4, base + 16384); LOADC(5, base + 16385);
            } else if (ady == 0 && adz == 0 && adx == 1) {
                MOVC(0,4); MOVC(1,5); MOVC(2,6); MOVC(3,7);
                LOADC(4, base + 16384); LOADC(5, base + 16385);
                LOADC(6, base + 16512); LOADC(7, base + 16513);
            } else if (ady == 0 && adz == 0 && adx == -1) {
                MOVC(4,0); MOVC(5,1); MOVC(6,2); MOVC(7,3);
                LOADC(0, base);       LOADC(1, base + 1);
                LOADC(2, base + 128); LOADC(3, base + 129);
            } else {
                LOADC(0, base);         LOADC(1, base + 1);
                LOADC(2, base + 128);   LOADC(3, base + 129);
                LOADC(4, base + 16384); LOADC(5, base + 16385);
                LOADC(6, base + 16512); LOADC(7, base + 16513);
            }
            ccx = lx; ccy = ly; ccz = lz;
        }

        const float gx1 = fx, gx0 = 1.0f - fx;
        const float gy1 = fy, gy0 = 1.0f - fy;
        const float gz1 = fz, gz0 = 1.0f - fz;
        float w[8];
        w[0] = gx0*gy0*gz0; w[1] = gx0*gy0*gz1; w[2] = gx0*gy1*gz0; w[3] = gx0*gy1*gz1;
        w[4] = gx1*gy0*gz0; w[5] = gx1*gy0*gz1; w[6] = gx1*gy1*gz0; w[7] = gx1*gy1*gz1;

        float sigma = 0, c0 = 0, c1 = 0, c2 = 0;
        #pragma unroll
        for (int c = 0; c < 8; c++) {
            sigma += w[c] * csig[c];
            c0    += w[c] * cr0[c];
            c1    += w[c] * cr1[c];
            c2    += w[c] * cr2[c];
        }

        const float la = -STEPSZ * fmaxf(sigma, 0.0f) * ds;
        const float e  = __expf(la);
        const float ws = light * (1.0f - e);
        c0 = fmaxf(c0 + 0.5f, 0.0f);
        c1 = fmaxf(c1 + 0.5f, 0.0f);
        c2 = fmaxf(c2 + 0.5f, 0.0f);

        aR += ws * c0; aG += ws * c1; aB += ws * c2;
        aA += ws;
        const float dd = t * ds;
        aD1 += ws * dd;
        aD2 += ws * dd * dd;
        light *= e;
        ll    += la;
    }

    // SoA partials: two float4 arrays, coalesced stores.
    const size_t pidx = (size_t)(seg * TILES + tile) * 64 + lane;
    float4* pa = (float4*)parts;
    float4* pb = pa + (size_t)NSEG * TILES * 64;
    pa[pidx] = make_float4(aR, aG, aB, aA);
    pb[pidx] = make_float4(aD1, aD2, ll, 0.0f);
}

// ---------------------------------------------------------------------------
// Stitch: one thread per ray combines its NSEG partials.
// ---------------------------------------------------------------------------
template <int NSEG>
__global__ __launch_bounds__(256)
void stitch_kernel(const float* __restrict__ parts, float* __restrict__ out)
{
    const int idx  = blockIdx.x * 256 + threadIdx.x;   // (tile, lane) id
    const int tile = idx >> 6;
    const int lane = idx & 63;
    const int ray  = (((tile >> 4) * 8 + (lane >> 3)) << 7)
                   + ((tile & 15) << 3) + (lane & 7);

    const float4* pa = (const float4*)parts;
    const float4* pb = pa + (size_t)NSEG * TILES * 64;

    float pre = 0.0f;
    float R = 0, G = 0, B = 0, A = 0, D1 = 0, D2 = 0;
    #pragma unroll 4
    for (int s = 0; s < NSEG; s++) {
        const size_t pidx = (size_t)(s * TILES + tile) * 64 + lane;
        const float4 a = pa[pidx];
        const float4 b = pb[pidx];
        const float T = __expf(pre);
        R  += T * a.x;  G  += T * a.y;  B  += T * a.z;  A += T * a.w;
        D1 += T * b.x;  D2 += T * b.y;
        pre += b.z;
    }

    const float bg    = __expf(pre);
    const float denom = fmaxf(A, 1e-10f);
    const float E     = D1 / denom;
    const float ov    = D2 - 2.0f * E * D1 + E * E * A;

    const int o = ray * 6;
    out[o + 0] = R + bg;
    out[o + 1] = G + bg;
    out[o + 2] = B + bg;
    out[o + 3] = A;
    out[o + 4] = E;
    out[o + 5] = ov / denom;
}

// ---------------------------------------------------------------------------
// Fallback (no workspace): verified round-1 math, direct links/density/sh
// reads, wave = 1 ray with shfl stitch.
// ---------------------------------------------------------------------------
__global__ __launch_bounds__(256, 8)
void march_fallback_kernel(const float* __restrict__ origins,
                           const float* __restrict__ dirs,
                           const int*   __restrict__ links,
                           const float* __restrict__ density,
                           const float* __restrict__ sh,
                           float* __restrict__ out)
{
    const int tid  = threadIdx.x;
    const int lane = tid & 63;
    const int r    = tid >> 6;
    const int ray  = blockIdx.x * 4 + r;

    const float owx = origins[ray * 3 + 0];
    const float owy = origins[ray * 3 + 1];
    const float owz = origins[ray * 3 + 2];
    const float dwx = dirs[ray * 3 + 0];
    const float dwy = dirs[ray * 3 + 1];
    const float dwz = dirs[ray * 3 + 2];

    const float invn = 1.0f / sqrtf(dwx * dwx + dwy * dwy + dwz * dwz);
    const float vx = dwx * invn, vy = dwy * invn, vz = dwz * invn;
    const float ox = 63.5f + owx * 64.0f;
    const float oy = 63.5f + owy * 64.0f;
    const float oz = 63.5f + owz * 64.0f;
    const float sxx = vx * 64.0f, syy = vy * 64.0f, szz = vz * 64.0f;
    const float ds  = 1.0f / sqrtf(sxx * sxx + syy * syy + szz * szz);
    const float dx = sxx * ds, dy = syy * ds, dz = szz * ds;

    float shm[9];
    shm[0] = 0.28209479177387814f;
    shm[1] = -0.4886025119029199f * vy;
    shm[2] =  0.4886025119029199f * vz;
    shm[3] = -0.4886025119029199f * vx;
    shm[4] =  1.0925484305920792f * vx * vy;
    shm[5] = -1.0925484305920792f * vy * vz;
    shm[6] =  0.31539156525252005f * (2.0f * vz * vz - vx * vx - vy * vy);
    shm[7] = -1.0925484305920792f * vx * vz;
    shm[8] =  0.5462742152960396f * (vx * vx - vy * vy);

    float t0 = 0.0f, tmax = 1e9f;
    {
        const float o3[3] = { ox, oy, oz };
        const float d3[3] = { dx, dy, dz };
        #pragma unroll
        for (int a = 0; a < 3; a++) {
            if (d3[a] != 0.0f) {
                float inv = 1.0f / d3[a];
                float ta = (-0.5f  - o3[a]) * inv;
                float tb = (127.5f - o3[a]) * inv;
                t0   = fmaxf(t0,   fminf(ta, tb));
                tmax = fminf(tmax, fmaxf(ta, tb));
            }
        }
    }

    float ll = 0.0f, light = 1.0f;
    float aR = 0, aG = 0, aB = 0, aA = 0, aD1 = 0, aD2 = 0;
    int cached_cell = -1;
    float csig[8], cr0[8], cr1[8], cr2[8];

    const int k0 = lane * (MAXSTEPS / 64);
    for (int i = 0; i < MAXSTEPS / 64; i++) {
        const float t = t0 + (float)(k0 + i) * STEPSZ;
        if (t > tmax) break;

        float px = fminf(fmaxf(ox + t * dx, 0.0f), 127.0f);
        float py = fminf(fmaxf(oy + t * dy, 0.0f), 127.0f);
        float pz = fminf(fmaxf(oz + t * dz, 0.0f), 127.0f);
        const int lx = min(max((int)px, 0), 126);
        const int ly = min(max((int)py, 0), 126);
        const int lz = min(max((int)pz, 0), 126);
        const float fx = px - (float)lx;
        const float fy = py - (float)ly;
        const float fz = pz - (float)lz;

        const int cell = (lx << 14) | (ly << 7) | lz;
        if (cell != cached_cell) {
            cached_cell = cell;
            #pragma unroll
            for (int c = 0; c < 8; c++) {
                const int cdx = (c >> 2) & 1, cdy = (c >> 1) & 1, cdz = c & 1;
                const int idx = cell + (cdx << 14) + (cdy << 7) + cdz;
                const int lnk = links[idx];
                float sg = 0, q0 = 0, q1 = 0, q2 = 0;
                if (lnk >= 0) {
                    sg = density[lnk];
                    const float* row = sh + (size_t)lnk * 27;
                    #pragma unroll
                    for (int k = 0; k < 9; k++) {
                        const float m = shm[k];
                        q0 += m * row[k];
                        q1 += m * row[9 + k];
                        q2 += m * row[18 + k];
                    }
                }
                csig[c] = sg; cr0[c] = q0; cr1[c] = q1; cr2[c] = q2;
            }
        }

        const float gx1 = fx, gx0 = 1.0f - fx;
        const float gy1 = fy, gy0 = 1.0f - fy;
        const float gz1 = fz, gz0 = 1.0f - fz;
        float w[8];
        w[0] = gx0*gy0*gz0; w[1] = gx0*gy0*gz1; w[2] = gx0*gy1*gz0; w[3] = gx0*gy1*gz1;
        w[4] = gx1*gy0*gz0; w[5] = gx1*gy0*gz1; w[6] = gx1*gy1*gz0; w[7] = gx1*gy1*gz1;

        float sigma = 0, c0 = 0, c1 = 0, c2 = 0;
        #pragma unroll
        for (int c = 0; c < 8; c++) {
            sigma += w[c] * csig[c];
            c0    += w[c] * cr0[c];
            c1    += w[c] * cr1[c];
            c2    += w[c] * cr2[c];
        }

        const float la = -STEPSZ * fmaxf(sigma, 0.0f) * ds;
        const float e  = __expf(la);
        const float ws = light * (1.0f - e);
        c0 = fmaxf(c0 + 0.5f, 0.0f);
        c1 = fmaxf(c1 + 0.5f, 0.0f);
        c2 = fmaxf(c2 + 0.5f, 0.0f);

        aR += ws * c0; aG += ws * c1; aB += ws * c2;
        aA += ws;
        const float dd = t * ds;
        aD1 += ws * dd;
        aD2 += ws * dd * dd;
        light *= e;
        ll    += la;
    }

    float inc = ll;
    #pragma unroll
    for (int off = 1; off < 64; off <<= 1) {
        const float v = __shfl_up(inc, off, 64);
        if (lane >= off) inc += v;
    }
    const float pre = inc - ll;
    const float T   = __expf(pre);
    aR *= T; aG *= T; aB *= T; aA *= T; aD1 *= T; aD2 *= T;

    #pragma unroll
    for (int off = 32; off; off >>= 1) {
        aR  += __shfl_xor(aR,  off, 64);
        aG  += __shfl_xor(aG,  off, 64);
        aB  += __shfl_xor(aB,  off, 64);
        aA  += __shfl_xor(aA,  off, 64);
        aD1 += __shfl_xor(aD1, off, 64);
        aD2 += __shfl_xor(aD2, off, 64);
    }
    const float llt = __shfl(inc, 63, 64);

    if (lane == 0) {
        const float bg    = __expf(llt);
        const float denom = fmaxf(aA, 1e-10f);
        const float E     = aD1 / denom;
        const float ov    = aD2 - 2.0f * E * aD1 + E * E * aA;
        const int o = ray * 6;
        out[o + 0] = aR + bg;
        out[o + 1] = aG + bg;
        out[o + 2] = aB + bg;
        out[o + 3] = aA;
        out[o + 4] = E;
        out[o + 5] = ov / denom;
    }
}

extern "C" void kernel_launch(void* const* d_in, const int* in_sizes, int n_in,
                              void* d_out, int out_size, void* d_ws, size_t ws_size,
                              hipStream_t stream) {
    const float* origins = (const float*)d_in[0];
    const float* dirs    = (const float*)d_in[1];
    const int*   links   = (const int*)d_in[2];
    const float* density = (const float*)d_in[3];
    const float* sh      = (const float*)d_in[4];
    float* out = (float*)d_out;

    if (ws_size >= PACK_BYTES + part_bytes(32)) {
        _Float16* pack  = (_Float16*)d_ws;
        float*    parts = (float*)((char*)d_ws + PACK_BYTES);
        repack_kernel<<<dim3(NVOX / 256), dim3(256), 0, stream>>>(links, density, sh, pack);
        march_part_kernel<32><<<dim3(TILES * 32 / WPB), dim3(256), 0, stream>>>(
            origins, dirs, pack, parts);
        stitch_kernel<32><<<dim3(NRAYS / 256), dim3(256), 0, stream>>>(parts, out);
    } else if (ws_size >= PACK_BYTES + part_bytes(16)) {
        _Float16* pack  = (_Float16*)d_ws;
        float*    parts = (float*)((char*)d_ws + PACK_BYTES);
        repack_kernel<<<dim3(NVOX / 256), dim3(256), 0, stream>>>(links, density, sh, pack);
        march_part_kernel<16><<<dim3(TILES * 16 / WPB), dim3(256), 0, stream>>>(
            origins, dirs, pack, parts);
        stitch_kernel<16><<<dim3(NRAYS / 256), dim3(256), 0, stream>>>(parts, out);
    } else {
        march_fallback_kernel<<<dim3(NRAYS / 4), dim3(256), 0, stream>>>(
            origins, dirs, links, density, sh, out);
    }
}

// Round 5
// 669.288 us; speedup vs baseline: 3.5224x; 3.5224x over previous
//
#include <hip/hip_runtime.h>
#include <math.h>

#define GRIDN    128
#define NRAYS    16384
#define STEPSZ   0.5f
#define MAXSTEPS 320
#define NVOX     (GRIDN * GRIDN * GRIDN)
// fp16 record: 32 halves (64 B) per VOXEL: [0]=density, [1..27]=sh, pad.
// Voxel-indexed (links folded in at repack time); empty voxels = zero record.
#define PACK_BYTES ((size_t)(NVOX + 1) * 64)

// ---- tile/segment decomposition for the march ----
#define TILES  256                  // 16x16 tiles of 8x8 pixels
#define WPB    4                    // waves per block

static inline size_t part_bytes(int nseg) {
    return (size_t)nseg * TILES * 64 * 8 * 4;
}

typedef _Float16 half8 __attribute__((ext_vector_type(8)));

// ---------------------------------------------------------------------------
// Prologue: voxel-indexed repack, v4. Same LDS-assembly + coalesced-store
// structure as v3, but the sh read is now float4 (16 B/lane) instead of
// scalar fp32 (4 B/lane) — the scalar read was the one invariant across all
// previous (slow) repack versions. 256 voxels/block = 1728 float4, exactly.
// ---------------------------------------------------------------------------
__global__ __launch_bounds__(256, 8)
void repack_kernel(const int*   __restrict__ links,
                   const float* __restrict__ density,
                   const float* __restrict__ sh,
                   _Float16*    __restrict__ pack)
{
    __shared__ _Float16 rec[256 * 32];   // 16 KB: 256 records
    const int tid   = threadIdx.x;
    const int vbase = blockIdx.x * 256;

    // Phase 1: vectorized coalesced read of the block's 256 sh rows
    // (256*27 floats = 1728 float4; span is 16B-aligned: 256*108 % 16 == 0),
    // fp16-convert, scatter into record layout in LDS (~2-way banks, free).
    const float4* src4 = (const float4*)(sh + (size_t)vbase * 27);
    #pragma unroll
    for (int it = 0; it < 7; it++) {
        const int idx = it * 256 + tid;          // float4 index within block
        if (idx < 1728) {
            const float4 v = src4[idx];
            const int n0 = idx * 4;
            const float vv[4] = { v.x, v.y, v.z, v.w };
            #pragma unroll
            for (int e = 0; e < 4; e++) {
                const int n   = n0 + e;
                const int row = n / 27;          // compiler magic-mul
                const int k   = n - row * 27;
                rec[row * 32 + 1 + k] = (_Float16)vv[e];
            }
        }
    }

    const int lnk  = links[vbase + tid];
    const float dens = (lnk >= 0) ? density[lnk] : 0.0f;

    __syncthreads();

    // General-links fixup: if lnk != own row, capture correct data first.
    // (Identity links — the common case — never takes this path.)
    const bool fix = (lnk >= 0) && (lnk != vbase + tid);
    float tmp[27];
    if (fix) {
        if (lnk >= vbase && lnk < vbase + 256) {
            const _Float16* s = rec + (lnk - vbase) * 32 + 1;
            #pragma unroll
            for (int k = 0; k < 27; k++) tmp[k] = (float)s[k];
        } else {
            const float* row = sh + (size_t)lnk * 27;
            #pragma unroll
            for (int k = 0; k < 27; k++) tmp[k] = row[k];
        }
    }
    __syncthreads();

    _Float16* my = rec + tid * 32;
    my[0]  = (_Float16)dens;
    my[28] = (_Float16)0.0f; my[29] = (_Float16)0.0f;
    my[30] = (_Float16)0.0f; my[31] = (_Float16)0.0f;
    if (lnk < 0) {
        #pragma unroll
        for (int k = 0; k < 27; k++) my[1 + k] = (_Float16)0.0f;
    } else if (fix) {
        #pragma unroll
        for (int k = 0; k < 27; k++) my[1 + k] = (_Float16)tmp[k];
    }
    __syncthreads();

    // Phase 3: fully coalesced LDS->global copy (16 KB / block).
    const uint4* ls = (const uint4*)rec;
    uint4* gd = (uint4*)(pack + (size_t)vbase * 32);
    #pragma unroll
    for (int i = 0; i < 4; i++)
        gd[i * 256 + tid] = ls[i * 256 + tid];
}

// ---------------------------------------------------------------------------
// March partials: EXACT round-3 structure (proven 335 us, VGPR=32, no
// scratch). One wave = 64 adjacent rays (8x8 pixel tile) at ONE segment.
// Whole-cell cached corner projections; full 8-corner reload on cell change.
// (Round-4's branchy incremental cache spilled the corner arrays to scratch
//  — WRITE_SIZE 3.36 GB — and ran 6x slower. Do not reintroduce partial
//  array updates under divergent control flow.)
// Partials in SoA float4 arrays so stores/loads coalesce.
// ---------------------------------------------------------------------------
template <int NSEG>
__global__ __launch_bounds__(256, 8)
void march_part_kernel(const float* __restrict__ origins,
                       const float* __restrict__ dirs,
                       const _Float16* __restrict__ pack,
                       float* __restrict__ parts)
{
    constexpr int SPSEG = MAXSTEPS / NSEG;
    const int lane = threadIdx.x & 63;
    const int gw   = blockIdx.x * WPB + (threadIdx.x >> 6);
    const int seg  = gw >> 8;              // seg-major dispatch: resident
    const int tile = gw & (TILES - 1);     //  waves share a depth slab
    const int ray  = (((tile >> 4) * 8 + (lane >> 3)) << 7)
                   + ((tile & 15) << 3) + (lane & 7);

    // ---- ray setup ----
    const float owx = origins[ray * 3 + 0];
    const float owy = origins[ray * 3 + 1];
    const float owz = origins[ray * 3 + 2];
    const float dwx = dirs[ray * 3 + 0];
    const float dwy = dirs[ray * 3 + 1];
    const float dwz = dirs[ray * 3 + 2];

    const float invn = 1.0f / sqrtf(dwx * dwx + dwy * dwy + dwz * dwz);
    const float vx = dwx * invn, vy = dwy * invn, vz = dwz * invn;

    const float ox = 63.5f + owx * 64.0f;
    const float oy = 63.5f + owy * 64.0f;
    const float oz = 63.5f + owz * 64.0f;

    const float sxx = vx * 64.0f, syy = vy * 64.0f, szz = vz * 64.0f;
    const float ds  = 1.0f / sqrtf(sxx * sxx + syy * syy + szz * szz);
    const float dx = sxx * ds, dy = syy * ds, dz = szz * ds;

    float shm[9];
    shm[0] = 0.28209479177387814f;
    shm[1] = -0.4886025119029199f * vy;
    shm[2] =  0.4886025119029199f * vz;
    shm[3] = -0.4886025119029199f * vx;
    shm[4] =  1.0925484305920792f * vx * vy;
    shm[5] = -1.0925484305920792f * vy * vz;
    shm[6] =  0.31539156525252005f * (2.0f * vz * vz - vx * vx - vy * vy);
    shm[7] = -1.0925484305920792f * vx * vz;
    shm[8] =  0.5462742152960396f * (vx * vx - vy * vy);

    float t0 = 0.0f, tmax = 1e9f;
    {
        const float o3[3] = { ox, oy, oz };
        const float d3[3] = { dx, dy, dz };
        #pragma unroll
        for (int a = 0; a < 3; a++) {
            if (d3[a] != 0.0f) {
                float inv = 1.0f / d3[a];
                float ta = (-0.5f  - o3[a]) * inv;
                float tb = (127.5f - o3[a]) * inv;
                t0   = fmaxf(t0,   fminf(ta, tb));
                tmax = fminf(tmax, fmaxf(ta, tb));
            }
        }
    }

    float ll = 0.0f;
    float light = 1.0f;
    float aR = 0, aG = 0, aB = 0, aA = 0, aD1 = 0, aD2 = 0;

    int cached_cell = -1;
    float csig[8], cr0[8], cr1[8], cr2[8];

    const int k0 = seg * SPSEG;
    for (int i = 0; i < SPSEG; i++) {
        const float t = t0 + (float)(k0 + i) * STEPSZ;
        if (t > tmax) break;

        float px = fminf(fmaxf(ox + t * dx, 0.0f), 127.0f);
        float py = fminf(fmaxf(oy + t * dy, 0.0f), 127.0f);
        float pz = fminf(fmaxf(oz + t * dz, 0.0f), 127.0f);
        const int lx = min(max((int)px, 0), 126);
        const int ly = min(max((int)py, 0), 126);
        const int lz = min(max((int)pz, 0), 126);
        const float fx = px - (float)lx;
        const float fy = py - (float)ly;
        const float fz = pz - (float)lz;

        const int cell = (lx << 14) | (ly << 7) | lz;
        if (cell != cached_cell) {
            cached_cell = cell;
            #pragma unroll
            for (int c = 0; c < 8; c++) {
                const int cdx = (c >> 2) & 1, cdy = (c >> 1) & 1, cdz = c & 1;
                const int vox = cell + (cdx << 14) + (cdy << 7) + cdz;
                const half8* pr = (const half8*)(pack + (size_t)vox * 32);
                const half8 h0 = pr[0], h1 = pr[1], h2 = pr[2], h3 = pr[3];
                csig[c] = (float)h0[0];
                cr0[c] = shm[0]*(float)h0[1] + shm[1]*(float)h0[2] + shm[2]*(float)h0[3]
                       + shm[3]*(float)h0[4] + shm[4]*(float)h0[5] + shm[5]*(float)h0[6]
                       + shm[6]*(float)h0[7] + shm[7]*(float)h1[0] + shm[8]*(float)h1[1];
                cr1[c] = shm[0]*(float)h1[2] + shm[1]*(float)h1[3] + shm[2]*(float)h1[4]
                       + shm[3]*(float)h1[5] + shm[4]*(float)h1[6] + shm[5]*(float)h1[7]
                       + shm[6]*(float)h2[0] + shm[7]*(float)h2[1] + shm[8]*(float)h2[2];
                cr2[c] = shm[0]*(float)h2[3] + shm[1]*(float)h2[4] + shm[2]*(float)h2[5]
                       + shm[3]*(float)h2[6] + shm[4]*(float)h2[7] + shm[5]*(float)h3[0]
                       + shm[6]*(float)h3[1] + shm[7]*(float)h3[2] + shm[8]*(float)h3[3];
            }
        }

        const float gx1 = fx, gx0 = 1.0f - fx;
        const float gy1 = fy, gy0 = 1.0f - fy;
        const float gz1 = fz, gz0 = 1.0f - fz;
        float w[8];
        w[0] = gx0*gy0*gz0; w[1] = gx0*gy0*gz1; w[2] = gx0*gy1*gz0; w[3] = gx0*gy1*gz1;
        w[4] = gx1*gy0*gz0; w[5] = gx1*gy0*gz1; w[6] = gx1*gy1*gz0; w[7] = gx1*gy1*gz1;

        float sigma = 0, c0 = 0, c1 = 0, c2 = 0;
        #pragma unroll
        for (int c = 0; c < 8; c++) {
            sigma += w[c] * csig[c];
            c0    += w[c] * cr0[c];
            c1    += w[c] * cr1[c];
            c2    += w[c] * cr2[c];
        }

        const float la = -STEPSZ * fmaxf(sigma, 0.0f) * ds;
        const float e  = __expf(la);
        const float ws = light * (1.0f - e);
        c0 = fmaxf(c0 + 0.5f, 0.0f);
        c1 = fmaxf(c1 + 0.5f, 0.0f);
        c2 = fmaxf(c2 + 0.5f, 0.0f);

        aR += ws * c0; aG += ws * c1; aB += ws * c2;
        aA += ws;
        const float dd = t * ds;
        aD1 += ws * dd;
        aD2 += ws * dd * dd;
        light *= e;
        ll    += la;
    }

    // SoA partials: two float4 arrays, coalesced stores.
    const size_t pidx = (size_t)(seg * TILES + tile) * 64 + lane;
    float4* pa = (float4*)parts;
    float4* pb = pa + (size_t)NSEG * TILES * 64;
    pa[pidx] = make_float4(aR, aG, aB, aA);
    pb[pidx] = make_float4(aD1, aD2, ll, 0.0f);
}

// ---------------------------------------------------------------------------
// Stitch: one thread per ray combines its NSEG partials.
// ---------------------------------------------------------------------------
template <int NSEG>
__global__ __launch_bounds__(256)
void stitch_kernel(const float* __restrict__ parts, float* __restrict__ out)
{
    const int idx  = blockIdx.x * 256 + threadIdx.x;   // (tile, lane) id
    const int tile = idx >> 6;
    const int lane = idx & 63;
    const int ray  = (((tile >> 4) * 8 + (lane >> 3)) << 7)
                   + ((tile & 15) << 3) + (lane & 7);

    const float4* pa = (const float4*)parts;
    const float4* pb = pa + (size_t)NSEG * TILES * 64;

    float pre = 0.0f;
    float R = 0, G = 0, B = 0, A = 0, D1 = 0, D2 = 0;
    #pragma unroll 4
    for (int s = 0; s < NSEG; s++) {
        const size_t pidx = (size_t)(s * TILES + tile) * 64 + lane;
        const float4 a = pa[pidx];
        const float4 b = pb[pidx];
        const float T = __expf(pre);
        R  += T * a.x;  G  += T * a.y;  B  += T * a.z;  A += T * a.w;
        D1 += T * b.x;  D2 += T * b.y;
        pre += b.z;
    }

    const float bg    = __expf(pre);
    const float denom = fmaxf(A, 1e-10f);
    const float E     = D1 / denom;
    const float ov    = D2 - 2.0f * E * D1 + E * E * A;

    const int o = ray * 6;
    out[o + 0] = R + bg;
    out[o + 1] = G + bg;
    out[o + 2] = B + bg;
    out[o + 3] = A;
    out[o + 4] = E;
    out[o + 5] = ov / denom;
}

// ---------------------------------------------------------------------------
// Fallback (no workspace): verified round-1 math, direct links/density/sh
// reads, wave = 1 ray with shfl stitch.
// ---------------------------------------------------------------------------
__global__ __launch_bounds__(256, 8)
void march_fallback_kernel(const float* __restrict__ origins,
                           const float* __restrict__ dirs,
                           const int*   __restrict__ links,
                           const float* __restrict__ density,
                           const float* __restrict__ sh,
                           float* __restrict__ out)
{
    const int tid  = threadIdx.x;
    const int lane = tid & 63;
    const int r    = tid >> 6;
    const int ray  = blockIdx.x * 4 + r;

    const float owx = origins[ray * 3 + 0];
    const float owy = origins[ray * 3 + 1];
    const float owz = origins[ray * 3 + 2];
    const float dwx = dirs[ray * 3 + 0];
    const float dwy = dirs[ray * 3 + 1];
    const float dwz = dirs[ray * 3 + 2];

    const float invn = 1.0f / sqrtf(dwx * dwx + dwy * dwy + dwz * dwz);
    const float vx = dwx * invn, vy = dwy * invn, vz = dwz * invn;
    const float ox = 63.5f + owx * 64.0f;
    const float oy = 63.5f + owy * 64.0f;
    const float oz = 63.5f + owz * 64.0f;
    const float sxx = vx * 64.0f, syy = vy * 64.0f, szz = vz * 64.0f;
    const float ds  = 1.0f / sqrtf(sxx * sxx + syy * syy + szz * szz);
    const float dx = sxx * ds, dy = syy * ds, dz = szz * ds;

    float shm[9];
    shm[0] = 0.28209479177387814f;
    shm[1] = -0.4886025119029199f * vy;
    shm[2] =  0.4886025119029199f * vz;
    shm[3] = -0.4886025119029199f * vx;
    shm[4] =  1.0925484305920792f * vx * vy;
    shm[5] = -1.0925484305920792f * vy * vz;
    shm[6] =  0.31539156525252005f * (2.0f * vz * vz - vx * vx - vy * vy);
    shm[7] = -1.0925484305920792f * vx * vz;
    shm[8] =  0.5462742152960396f * (vx * vx - vy * vy);

    float t0 = 0.0f, tmax = 1e9f;
    {
        const float o3[3] = { ox, oy, oz };
        const float d3[3] = { dx, dy, dz };
        #pragma unroll
        for (int a = 0; a < 3; a++) {
            if (d3[a] != 0.0f) {
                float inv = 1.0f / d3[a];
                float ta = (-0.5f  - o3[a]) * inv;
                float tb = (127.5f - o3[a]) * inv;
                t0   = fmaxf(t0,   fminf(ta, tb));
                tmax = fminf(tmax, fmaxf(ta, tb));
            }
        }
    }

    float ll = 0.0f, light = 1.0f;
    float aR = 0, aG = 0, aB = 0, aA = 0, aD1 = 0, aD2 = 0;
    int cached_cell = -1;
    float csig[8], cr0[8], cr1[8], cr2[8];

    const int k0 = lane * (MAXSTEPS / 64);
    for (int i = 0; i < MAXSTEPS / 64; i++) {
        const float t = t0 + (float)(k0 + i) * STEPSZ;
        if (t > tmax) break;

        float px = fminf(fmaxf(ox + t * dx, 0.0f), 127.0f);
        float py = fminf(fmaxf(oy + t * dy, 0.0f), 127.0f);
        float pz = fminf(fmaxf(oz + t * dz, 0.0f), 127.0f);
        const int lx = min(max((int)px, 0), 126);
        const int ly = min(max((int)py, 0), 126);
        const int lz = min(max((int)pz, 0), 126);
        const float fx = px - (float)lx;
        const float fy = py - (float)ly;
        const float fz = pz - (float)lz;

        const int cell = (lx << 14) | (ly << 7) | lz;
        if (cell != cached_cell) {
            cached_cell = cell;
            #pragma unroll
            for (int c = 0; c < 8; c++) {
                const int cdx = (c >> 2) & 1, cdy = (c >> 1) & 1, cdz = c & 1;
                const int idx = cell + (cdx << 14) + (cdy << 7) + cdz;
                const int lnk = links[idx];
                float sg = 0, q0 = 0, q1 = 0, q2 = 0;
                if (lnk >= 0) {
                    sg = density[lnk];
                    const float* row = sh + (size_t)lnk * 27;
                    #pragma unroll
                    for (int k = 0; k < 9; k++) {
                        const float m = shm[k];
                        q0 += m * row[k];
                        q1 += m * row[9 + k];
                        q2 += m * row[18 + k];
                    }
                }
                csig[c] = sg; cr0[c] = q0; cr1[c] = q1; cr2[c] = q2;
            }
        }

        const float gx1 = fx, gx0 = 1.0f - fx;
        const float gy1 = fy, gy0 = 1.0f - fy;
        const float gz1 = fz, gz0 = 1.0f - fz;
        float w[8];
        w[0] = gx0*gy0*gz0; w[1] = gx0*gy0*gz1; w[2] = gx0*gy1*gz0; w[3] = gx0*gy1*gz1;
        w[4] = gx1*gy0*gz0; w[5] = gx1*gy0*gz1; w[6] = gx1*gy1*gz0; w[7] = gx1*gy1*gz1;

        float sigma = 0, c0 = 0, c1 = 0, c2 = 0;
        #pragma unroll
        for (int c = 0; c < 8; c++) {
            sigma += w[c] * csig[c];
            c0    += w[c] * cr0[c];
            c1    += w[c] * cr1[c];
            c2    += w[c] * cr2[c];
        }

        const float la = -STEPSZ * fmaxf(sigma, 0.0f) * ds;
        const float e  = __expf(la);
        const float ws = light * (1.0f - e);
        c0 = fmaxf(c0 + 0.5f, 0.0f);
        c1 = fmaxf(c1 + 0.5f, 0.0f);
        c2 = fmaxf(c2 + 0.5f, 0.0f);

        aR += ws * c0; aG += ws * c1; aB += ws * c2;
        aA += ws;
        const float dd = t * ds;
        aD1 += ws * dd;
        aD2 += ws * dd * dd;
        light *= e;
        ll    += la;
    }

    float inc = ll;
    #pragma unroll
    for (int off = 1; off < 64; off <<= 1) {
        const float v = __shfl_up(inc, off, 64);
        if (lane >= off) inc += v;
    }
    const float pre = inc - ll;
    const float T   = __expf(pre);
    aR *= T; aG *= T; aB *= T; aA *= T; aD1 *= T; aD2 *= T;

    #pragma unroll
    for (int off = 32; off; off >>= 1) {
        aR  += __shfl_xor(aR,  off, 64);
        aG  += __shfl_xor(aG,  off, 64);
        aB  += __shfl_xor(aB,  off, 64);
        aA  += __shfl_xor(aA,  off, 64);
        aD1 += __shfl_xor(aD1, off, 64);
        aD2 += __shfl_xor(aD2, off, 64);
    }
    const float llt = __shfl(inc, 63, 64);

    if (lane == 0) {
        const float bg    = __expf(llt);
        const float denom = fmaxf(aA, 1e-10f);
        const float E     = aD1 / denom;
        const float ov    = aD2 - 2.0f * E * aD1 + E * E * aA;
        const int o = ray * 6;
        out[o + 0] = aR + bg;
        out[o + 1] = aG + bg;
        out[o + 2] = aB + bg;
        out[o + 3] = aA;
        out[o + 4] = E;
        out[o + 5] = ov / denom;
    }
}

extern "C" void kernel_launch(void* const* d_in, const int* in_sizes, int n_in,
                              void* d_out, int out_size, void* d_ws, size_t ws_size,
                              hipStream_t stream) {
    const float* origins = (const float*)d_in[0];
    const float* dirs    = (const float*)d_in[1];
    const int*   links   = (const int*)d_in[2];
    const float* density = (const float*)d_in[3];
    const float* sh      = (const float*)d_in[4];
    float* out = (float*)d_out;

    if (ws_size >= PACK_BYTES + part_bytes(32)) {
        _Float16* pack  = (_Float16*)d_ws;
        float*    parts = (float*)((char*)d_ws + PACK_BYTES);
        repack_kernel<<<dim3(NVOX / 256), dim3(256), 0, stream>>>(links, density, sh, pack);
        march_part_kernel<32><<<dim3(TILES * 32 / WPB), dim3(256), 0, stream>>>(
            origins, dirs, pack, parts);
        stitch_kernel<32><<<dim3(NRAYS / 256), dim3(256), 0, stream>>>(parts, out);
    } else if (ws_size >= PACK_BYTES + part_bytes(16)) {
        _Float16* pack  = (_Float16*)d_ws;
        float*    parts = (float*)((char*)d_ws + PACK_BYTES);
        repack_kernel<<<dim3(NVOX / 256), dim3(256), 0, stream>>>(links, density, sh, pack);
        march_part_kernel<16><<<dim3(TILES * 16 / WPB), dim3(256), 0, stream>>>(
            origins, dirs, pack, parts);
        stitch_kernel<16><<<dim3(NRAYS / 256), dim3(256), 0, stream>>>(parts, out);
    } else {
        march_fallback_kernel<<<dim3(NRAYS / 4), dim3(256), 0, stream>>>(
            origins, dirs, links, density, sh, out);
    }
}